// Round 20
// baseline (44.602 us; speedup 1.0000x reference)
//
#include <hip/hip_runtime.h>
#include <stdint.h>

constexpr int Dz = 96, Hy = 160, Wx = 160;
constexpr int NVOX = Dz * Hy * Wx;

// Wave-autonomous tile: 32d x 8w x 2h per WAVE; 2 waves per 128-thread block.
// Stage-1 footprint per wave: 6 z-rows x 3 y-rows x 56-dword aligned x-pitch.
constexpr int ZW = 6, YW = 3, XP = 56;          // LDS plane: [6][3][56] dwords
constexpr int ROWS = ZW * YW;                   // 18 (z,y) rows
constexpr int NCHUNK = ROWS * 14;               // 252 16B chunks per plane
constexpr int UI = 4;                           // chunk rounds (4*64 >= 252)
constexpr int WBUF = UI * 64 * 4;               // 1024 dwords per wave buffer

typedef float f32x4 __attribute__((ext_vector_type(4)));   // native vector for nontemporal builtin

#define WAIT_LGKM() do { asm volatile("s_waitcnt lgkmcnt(0)" ::: "memory"); \
                         __builtin_amdgcn_sched_barrier(0); } while (0)
#define FENCE() __builtin_amdgcn_sched_barrier(0)

__global__ __launch_bounds__(128) void st_fused_kernel(
    const float* __restrict__ src,
    const float* __restrict__ flows,
    const float* __restrict__ rfp,
    float* __restrict__ out)
{
    __shared__ float raw[2][WBUF];      // 8 KB: one summed-plane buffer per wave
    const int t = threadIdx.x;
    const int v = t >> 6;               // wave id 0..1
    const int lane = t & 63;

    // XCD-aware bijective swizzle (2400 = 8 x 300), then wave-linear tiling
    const int bid = blockIdx.x;
    const int swz = (bid & 7) * 300 + (bid >> 3);
    const int wid = swz * 2 + v;        // 0..4799
    const int wt = wid % 20;            // w-tile (8 w each)
    const int rest = wid / 20;
    const int dt = rest % 3;            // d-tile (32 d each)
    const int hp = rest / 3;            // h-pair 0..79
    const int w0w = wt * 8, d0 = dt * 32, h0 = hp * 2;
    const float rf = *rfp;

    const int Z0w = (19 * w0w) >> 5;
    const int X0 = 53 * dt;             // (53*d0)/32 exact
    const int X0a = X0 & ~3;            // 16B-aligned x origin
    const int YB = (159 * h0) / 160;

    // ---- 4 live chunk addresses (16B each), advanced by channel (plane) stride ----
    const char* ap[UI];
    {
        const char* fb = (const char*)flows + ((size_t)YB * Wx + X0a) * 4;
#pragma unroll
        for (int u = 0; u < UI; ++u) {
            int c = u * 64 + lane;
            if (c >= NCHUNK) c = NCHUNK - 1;     // tail dups (LDS junk, never read)
            int row = c / 14, ch = c - row * 14;
            int zr = row / 3, yr = row - zr * 3;
            ap[u] = fb + ((size_t)((Z0w + zr) * Hy + yr) * Wx) * 4 + ch * 16;
        }
    }

    // ---- channel staging: load same channel of all 3 flow stages, sum, commit.
    // NON-TEMPORAL: flows are stream-once data; keep them from evicting the
    // src slice (2.46 MB/XCD) out of the 4 MB per-XCD L2 (stage-2 gathers re-touch src).
    f32x4 nxt[3][UI];                   // 48 VGPR in flight
    auto issue_ch = [&]() {
#pragma unroll
        for (int i = 0; i < 3; ++i)
#pragma unroll
            for (int u = 0; u < UI; ++u)
                nxt[i][u] = __builtin_nontemporal_load(
                    (const f32x4*)(ap[u] + (size_t)i * (3u * NVOX * 4u)));
#pragma unroll
        for (int u = 0; u < UI; ++u) ap[u] += (size_t)NVOX * 4;   // next channel
    };
    float* const lb = &raw[v][0];
    auto commit_ch = [&]() {
        f32x4* lb4 = (f32x4*)lb;
#pragma unroll
        for (int u = 0; u < UI; ++u) {
            const f32x4 s = (nxt[0][u] + nxt[1][u]) + nxt[2][u];
            lb4[u * 64 + lane] = s;
        }
    };

    // ---- compute mapping: lanes vary d (stage-2 x axis = stride 1) ----
    const int dl = lane & 31;
    const int half = lane >> 5;         // picks w quartet
    const int d = d0 + dl;

    const float xf = (float)(53 * d) * (1.0f / 32.0f);
    const int   x0i = (int)xf;
    const float fx  = xf - (float)x0i;
    const int   xx  = x0i - X0a;        // 0..54
    const float wxa = 1.0f - fx, wxb = fx;

    // z-row factorization: all 4 k's (zz,zz+1) pairs live in 4 consecutive rows.
    int rowoff[4];
    float wkz[4][4];
    {
        int zzk[4]; float wz0k[4], wz1k[4];
#pragma unroll
        for (int k = 0; k < 4; ++k) {
            const int w = w0w + 4 * half + k;
            const float zf = (float)(19 * w) * (1.0f / 32.0f);
            const int z0i = (int)zf;
            const float fz = zf - (float)z0i;
            zzk[k] = z0i - Z0w;         // 0..4, nondecreasing in k
            wz0k[k] = 1.0f - fz; wz1k[k] = fz;
        }
        const int zz0 = zzk[0];
#pragma unroll
        for (int r = 0; r < 4; ++r) {
            rowoff[r] = min(zz0 + r, ZW - 1) * (YW * XP);
#pragma unroll
            for (int k = 0; k < 4; ++k) {
                const int rel = zzk[k] - zz0;            // 0..2
                wkz[r][k] = (rel == r) ? wz0k[k] : ((rel == r - 1) ? wz1k[k] : 0.0f);
            }
        }
    }

    float wyr[2][3];
#pragma unroll
    for (int j = 0; j < 2; ++j) {
        const int h = h0 + j;
        const float yf = (float)h * (159.0f / 160.0f);
        const int y0i = (int)yf;
        const float fy = yf - (float)y0i;
        const int yrel = y0i - YB;      // 0 or 1
        const float a = 1.0f - fy, b = fy;
        wyr[j][0] = (yrel == 0) ? a : 0.0f;
        wyr[j][1] = (yrel == 0) ? b : a;
        wyr[j][2] = (yrel == 0) ? 0.0f : b;
    }

    // 12 row-pair LDS reads per channel (one x-interp per distinct row);
    // sparse wkz scatters rows into the 4 k outputs.
    auto compute = [&](float (&acc)[4][2]) {
#pragma unroll
        for (int yy = 0; yy < 3; ++yy) {
            float zv0 = 0.f, zv1 = 0.f, zv2 = 0.f, zv3 = 0.f;
#pragma unroll
            for (int r = 0; r < 4; ++r) {
                const float* p = lb + rowoff[r] + yy * XP + xx;
                const float xv = wxa * p[0] + wxb * p[1];
                zv0 += wkz[r][0] * xv;
                zv1 += wkz[r][1] * xv;
                zv2 += wkz[r][2] * xv;
                zv3 += wkz[r][3] * xv;
            }
            acc[0][0] += wyr[0][yy] * zv0; acc[0][1] += wyr[1][yy] * zv0;
            acc[1][0] += wyr[0][yy] * zv1; acc[1][1] += wyr[1][yy] * zv1;
            acc[2][0] += wyr[0][yy] * zv2; acc[2][1] += wyr[1][yy] * zv2;
            acc[3][0] += wyr[0][yy] * zv3; acc[3][1] += wyr[1][yy] * zv3;
        }
    };

    float accA[4][2], accB[4][2], accC[4][2];
#pragma unroll
    for (int k = 0; k < 4; ++k)
#pragma unroll
        for (int j = 0; j < 2; ++j) { accA[k][j] = 0.f; accB[k][j] = 0.f; accC[k][j] = 0.f; }

    // ---- 3-phase pipeline: loads of ch c+1 in flight under compute of ch c.
    // Same-wave LDS ordering makes the single buffer safe (write after prior read).
    issue_ch();            // ch0
    commit_ch();
    issue_ch();            // ch1
    compute(accA);         // ch0; ch1 loads in flight
    FENCE();
    commit_ch();
    issue_ch();            // ch2
    compute(accB);         // ch1; ch2 loads in flight
    FENCE();
    commit_ch();
    compute(accC);         // ch2

    // ---- stage 2: row-paired src sampling (zeros mode); results straight to
    // wave-private transpose LDS (same-wave ordering) ----
    float* tr = &raw[v][0];             // 2 tiles of [32][9] dwords (576 <= 1024)
#pragma unroll
    for (int j = 0; j < 2; ++j) {
        const int h = h0 + j;
#pragma unroll
        for (int k = 0; k < 4; ++k) {
            const int w = w0w + 4 * half + k;
            const float f0 = (float)d + accA[k][j] * rf;   // -> x axis of src
            const float f1 = (float)h + accB[k][j] * rf;   // -> y axis
            const float f2 = (float)w + accC[k][j] * rf;   // -> z axis

            const float xs = f0 * (159.0f / 95.0f);
            const float ys = f1;
            const float zs = f2 * (95.0f / 159.0f);

            const float xf0 = floorf(xs), yf0 = floorf(ys), zf0 = floorf(zs);
            const float gx = xs - xf0, gy = ys - yf0, gz = zs - zf0;
            const int xi0 = (int)xf0, yi0 = (int)yf0, zi0 = (int)zf0;

            const int xc = min(max(xi0, 0), Wx - 2);
            const bool sx0 = (xi0 == xc);
            const float wx0m = ((unsigned)xi0 < (unsigned)Wx) ? (1.0f - gx) : 0.0f;
            const float wx1m = ((unsigned)(xi0 + 1) < (unsigned)Wx) ? gx : 0.0f;

            const int yc0 = min(max(yi0, 0), Hy - 1);
            const int yc1 = min(max(yi0 + 1, 0), Hy - 1);
            const int zc0 = min(max(zi0, 0), Dz - 1);
            const int zc1 = min(max(zi0 + 1, 0), Dz - 1);
            const float wy0m = ((unsigned)yi0 < (unsigned)Hy) ? (1.0f - gy) : 0.0f;
            const float wy1m = ((unsigned)(yi0 + 1) < (unsigned)Hy) ? gy : 0.0f;
            const float wz0m = ((unsigned)zi0 < (unsigned)Dz) ? (1.0f - gz) : 0.0f;
            const float wz1m = ((unsigned)(zi0 + 1) < (unsigned)Dz) ? gz : 0.0f;

            const float w00 = wz0m * wy0m, w01 = wz0m * wy1m;
            const float w10 = wz1m * wy0m, w11 = wz1m * wy1m;

            float r = 0.0f;
            auto rowadd = [&](int zc, int yc, float wt) {
                const float* p = src + ((size_t)zc * Hy + yc) * Wx + xc;
                const float va = p[0], vb = p[1];
                const float s0 = sx0 ? va : vb;   // value at xi0 (xi0==159 -> vb)
                const float s1 = sx0 ? vb : va;   // value at xi1 (xi0==-1 -> va)
                r += wt * (wx0m * s0 + wx1m * s1);
            };
            rowadd(zc0, yc0, w00);
            rowadd(zc0, yc1, w01);
            rowadd(zc1, yc0, w10);
            rowadd(zc1, yc1, w11);

            tr[j * 288 + dl * 9 + 4 * half + k] = r;
        }
    }
    WAIT_LGKM();

    const int rrow = lane >> 3;         // 0..7
    const int rcol = lane & 7;          // 0..7
#pragma unroll
    for (int j = 0; j < 2; ++j)
#pragma unroll
        for (int m = 0; m < 4; ++m) {
            const int dr = m * 8 + rrow;
            out[((size_t)(d0 + dr) * Hy + (h0 + j)) * Wx + (w0w + rcol)] =
                tr[j * 288 + dr * 9 + rcol];
        }
}

extern "C" void kernel_launch(void* const* d_in, const int* in_sizes, int n_in,
                              void* d_out, int out_size, void* d_ws, size_t ws_size,
                              hipStream_t stream) {
    const float* src   = (const float*)d_in[0];
    const float* flows = (const float*)d_in[1];
    const float* rfp   = (const float*)d_in[2];
    float* out = (float*)d_out;

    st_fused_kernel<<<dim3(2400), 128, 0, stream>>>(src, flows, rfp, out);
}

// Round 21
// 35.487 us; speedup vs baseline: 1.2569x; 1.2569x over previous
//
#include <hip/hip_runtime.h>
#include <stdint.h>

constexpr int Dz = 96, Hy = 160, Wx = 160;
constexpr int NVOX = Dz * Hy * Wx;

// Wave-autonomous tile: 32d x 8w x 4h per WAVE; 2 waves per 128-thread block.
// Stage-1 footprint per wave: 6 z-rows x 5 y-rows x 56-dword aligned x-pitch.
constexpr int ZW = 6, YW = 5, XP = 56;          // LDS plane: [6][5][56] dwords
constexpr int ROWS = ZW * YW;                   // 30 (z,y) rows
constexpr int NCHUNK = ROWS * 14;               // 420 16B chunks per plane
constexpr int UI = 7;                           // chunk rounds (7*64 >= 420)
constexpr int WBUF = UI * 64 * 4;               // 1792 dwords per wave buffer

#define WAIT_LGKM() do { asm volatile("s_waitcnt lgkmcnt(0)" ::: "memory"); \
                         __builtin_amdgcn_sched_barrier(0); } while (0)

__global__ __launch_bounds__(128) void st_fused_kernel(
    const float* __restrict__ src,
    const float* __restrict__ flows,
    const float* __restrict__ rfp,
    float* __restrict__ out)
{
    __shared__ float raw[2][WBUF];      // 14336 B: one summed-plane buffer per wave
    const int t = threadIdx.x;
    const int v = t >> 6;               // wave id 0..1
    const int lane = t & 63;

    // XCD-aware bijective swizzle (1200 = 8 x 150), then wave-linear tiling
    const int bid = blockIdx.x;
    const int swz = (bid & 7) * 150 + (bid >> 3);
    const int wid = swz * 2 + v;        // 0..2399
    const int wt = wid % 20;            // w-tile (8 w each)
    const int rest = wid / 20;
    const int dt = rest % 3;            // d-tile (32 d each)
    const int hq = rest / 3;            // h-quad 0..39
    const int w0w = wt * 8, d0 = dt * 32, h0 = hq * 4;
    const float rf = *rfp;

    const int Z0w = (19 * w0w) >> 5;
    const int X0 = 53 * dt;             // (53*d0)/32 exact
    const int X0a = X0 & ~3;            // 16B-aligned x origin
    const int YB = (159 * h0) / 160;    // y rows YB..YB+4 cover all 4 h's (yrel<=3, +1 -> row 4)

    // ---- 7 per-lane chunk addresses (16B each), advanced by channel stride ----
    const char* ap[UI];
    {
        const char* fb = (const char*)flows + ((size_t)YB * Wx + X0a) * 4;
#pragma unroll
        for (int u = 0; u < UI; ++u) {
            int c = u * 64 + lane;
            if (c >= NCHUNK) c = NCHUNK - 1;     // tail dups (LDS junk, never read)
            int row = c / 14, ch = c - row * 14;
            int zr = row / YW, yr = row - zr * YW;
            ap[u] = fb + ((size_t)((Z0w + zr) * Hy + yr) * Wx) * 4 + ch * 16;
        }
    }

    // ---- channel staging: sum the 3 flow stages before interp (linearity),
    // store into the single per-wave buffer. Same-wave in-order LDS makes the
    // single buffer safe; compiler pipelines the 21 loads per channel.
    float* const lb = &raw[v][0];
    auto stage_ch = [&]() {
        float4* lb4 = (float4*)lb;
#pragma unroll
        for (int u = 0; u < UI; ++u) {
            const float4 s0 = *(const float4*)(ap[u]);
            const float4 s1 = *(const float4*)(ap[u] + (size_t)3 * NVOX * 4);
            const float4 s2 = *(const float4*)(ap[u] + (size_t)6 * NVOX * 4);
            float4 s;
            s.x = (s0.x + s1.x) + s2.x;
            s.y = (s0.y + s1.y) + s2.y;
            s.z = (s0.z + s1.z) + s2.z;
            s.w = (s0.w + s1.w) + s2.w;
            lb4[u * 64 + lane] = s;
        }
#pragma unroll
        for (int u = 0; u < UI; ++u) ap[u] += (size_t)NVOX * 4;   // next channel
    };

    // ---- compute mapping: lanes vary d (stage-2 x axis = stride 1) ----
    const int dl = lane & 31;
    const int half = lane >> 5;         // picks w quartet
    const int d = d0 + dl;

    const float xf = (float)(53 * d) * (1.0f / 32.0f);
    const int   x0i = (int)xf;
    const float fx  = xf - (float)x0i;
    const int   xx  = x0i - X0a;        // 0..54
    const float wxa = 1.0f - fx, wxb = fx;

    // z-row factorization: all 4 k's (zz,zz+1) pairs live in 4 consecutive rows.
    int rowoff[4];
    float wkz[4][4];
    {
        int zzk[4]; float wz0k[4], wz1k[4];
#pragma unroll
        for (int k = 0; k < 4; ++k) {
            const int w = w0w + 4 * half + k;
            const float zf = (float)(19 * w) * (1.0f / 32.0f);
            const int z0i = (int)zf;
            const float fz = zf - (float)z0i;
            zzk[k] = z0i - Z0w;         // 0..4, nondecreasing in k
            wz0k[k] = 1.0f - fz; wz1k[k] = fz;
        }
        const int zz0 = zzk[0];
#pragma unroll
        for (int r = 0; r < 4; ++r) {
            rowoff[r] = min(zz0 + r, ZW - 1) * (YW * XP);
#pragma unroll
            for (int k = 0; k < 4; ++k) {
                const int rel = zzk[k] - zz0;            // 0..2
                wkz[r][k] = (rel == r) ? wz0k[k] : ((rel == r - 1) ? wz1k[k] : 0.0f);
            }
        }
    }

    // y weights: 4 h's against 5 footprint rows (each h uses rows yrel, yrel+1)
    float wyr[4][5];
#pragma unroll
    for (int j = 0; j < 4; ++j) {
        const int h = h0 + j;
        const float yf = (float)h * (159.0f / 160.0f);
        const int y0i = (int)yf;
        const float fy = yf - (float)y0i;
        const int yrel = y0i - YB;      // 0..3
#pragma unroll
        for (int yy = 0; yy < 5; ++yy)
            wyr[j][yy] = (yy == yrel) ? (1.0f - fy) : ((yy == yrel + 1) ? fy : 0.0f);
    }

    // 20 row-pair LDS reads per channel (one x-interp per distinct row);
    // wkz scatters rows into 4 k's; wyr scatters y-rows into 4 j's.
    auto compute = [&](float (&acc)[4][4]) {
#pragma unroll
        for (int yy = 0; yy < 5; ++yy) {
            float zv0 = 0.f, zv1 = 0.f, zv2 = 0.f, zv3 = 0.f;
#pragma unroll
            for (int r = 0; r < 4; ++r) {
                const float* p = lb + rowoff[r] + yy * XP + xx;
                const float xv = wxa * p[0] + wxb * p[1];
                zv0 += wkz[r][0] * xv;
                zv1 += wkz[r][1] * xv;
                zv2 += wkz[r][2] * xv;
                zv3 += wkz[r][3] * xv;
            }
#pragma unroll
            for (int j = 0; j < 4; ++j) {
                const float wy = wyr[j][yy];
                acc[0][j] += wy * zv0;
                acc[1][j] += wy * zv1;
                acc[2][j] += wy * zv2;
                acc[3][j] += wy * zv3;
            }
        }
    };

    float accA[4][4], accB[4][4], accC[4][4];
#pragma unroll
    for (int k = 0; k < 4; ++k)
#pragma unroll
        for (int j = 0; j < 4; ++j) { accA[k][j] = 0.f; accB[k][j] = 0.f; accC[k][j] = 0.f; }

    // ---- 3 channels: stage -> compute (same-wave LDS ordering; no barriers) ----
    stage_ch();
    compute(accA);
    stage_ch();
    compute(accB);
    stage_ch();
    compute(accC);

    // ---- stage 2: row-paired src sampling (zeros mode); results straight to
    // wave-private transpose LDS ----
    float* tr = &raw[v][0];             // 4 tiles of [32][9] dwords (1152 <= 1792)
#pragma unroll
    for (int j = 0; j < 4; ++j) {
        const int h = h0 + j;
#pragma unroll
        for (int k = 0; k < 4; ++k) {
            const int w = w0w + 4 * half + k;
            const float f0 = (float)d + accA[k][j] * rf;   // -> x axis of src
            const float f1 = (float)h + accB[k][j] * rf;   // -> y axis
            const float f2 = (float)w + accC[k][j] * rf;   // -> z axis

            const float xs = f0 * (159.0f / 95.0f);
            const float ys = f1;
            const float zs = f2 * (95.0f / 159.0f);

            const float xf0 = floorf(xs), yf0 = floorf(ys), zf0 = floorf(zs);
            const float gx = xs - xf0, gy = ys - yf0, gz = zs - zf0;
            const int xi0 = (int)xf0, yi0 = (int)yf0, zi0 = (int)zf0;

            const int xc = min(max(xi0, 0), Wx - 2);
            const bool sx0 = (xi0 == xc);
            const float wx0m = ((unsigned)xi0 < (unsigned)Wx) ? (1.0f - gx) : 0.0f;
            const float wx1m = ((unsigned)(xi0 + 1) < (unsigned)Wx) ? gx : 0.0f;

            const int yc0 = min(max(yi0, 0), Hy - 1);
            const int yc1 = min(max(yi0 + 1, 0), Hy - 1);
            const int zc0 = min(max(zi0, 0), Dz - 1);
            const int zc1 = min(max(zi0 + 1, 0), Dz - 1);
            const float wy0m = ((unsigned)yi0 < (unsigned)Hy) ? (1.0f - gy) : 0.0f;
            const float wy1m = ((unsigned)(yi0 + 1) < (unsigned)Hy) ? gy : 0.0f;
            const float wz0m = ((unsigned)zi0 < (unsigned)Dz) ? (1.0f - gz) : 0.0f;
            const float wz1m = ((unsigned)(zi0 + 1) < (unsigned)Dz) ? gz : 0.0f;

            const float w00 = wz0m * wy0m, w01 = wz0m * wy1m;
            const float w10 = wz1m * wy0m, w11 = wz1m * wy1m;

            float r = 0.0f;
            auto rowadd = [&](int zc, int yc, float wt) {
                const float* p = src + ((size_t)zc * Hy + yc) * Wx + xc;
                const float va = p[0], vb = p[1];
                const float s0 = sx0 ? va : vb;   // value at xi0 (xi0==159 -> vb)
                const float s1 = sx0 ? vb : va;   // value at xi1 (xi0==-1 -> va)
                r += wt * (wx0m * s0 + wx1m * s1);
            };
            rowadd(zc0, yc0, w00);
            rowadd(zc0, yc1, w01);
            rowadd(zc1, yc0, w10);
            rowadd(zc1, yc1, w11);

            tr[j * 288 + dl * 9 + 4 * half + k] = r;
        }
    }
    WAIT_LGKM();

    const int rrow = lane >> 3;         // 0..7
    const int rcol = lane & 7;          // 0..7
#pragma unroll
    for (int j = 0; j < 4; ++j)
#pragma unroll
        for (int m = 0; m < 4; ++m) {
            const int dr = m * 8 + rrow;
            out[((size_t)(d0 + dr) * Hy + (h0 + j)) * Wx + (w0w + rcol)] =
                tr[j * 288 + dr * 9 + rcol];
        }
}

extern "C" void kernel_launch(void* const* d_in, const int* in_sizes, int n_in,
                              void* d_out, int out_size, void* d_ws, size_t ws_size,
                              hipStream_t stream) {
    const float* src   = (const float*)d_in[0];
    const float* flows = (const float*)d_in[1];
    const float* rfp   = (const float*)d_in[2];
    float* out = (float*)d_out;

    st_fused_kernel<<<dim3(1200), 128, 0, stream>>>(src, flows, rfp, out);
}

// Round 22
// 29.104 us; speedup vs baseline: 1.5325x; 1.2193x over previous
//
#include <hip/hip_runtime.h>
#include <stdint.h>

constexpr int Dz = 96, Hy = 160, Wx = 160;
constexpr int NVOX = Dz * Hy * Wx;

// Block tile: 32d x 8w x 4h; 4 waves; wave v computes h = h0 + v (256 voxels).
// Stage-1 footprint (6z x 5y x 56x) staged ONCE per block, double-buffered
// channels, 3 barriers total. Combines r16's wave count with r21's bytes/voxel.
constexpr int ZW = 6, YW = 5, XP = 56;
constexpr int ROWS = ZW * YW;            // 30 (z,y) rows
constexpr int NCHUNK = ROWS * 14;        // 420 16B chunks per channel plane
constexpr int PL = ROWS * XP;            // 1680 dwords per channel buffer

#define WAIT_LGKM() do { asm volatile("s_waitcnt lgkmcnt(0)" ::: "memory"); \
                         __builtin_amdgcn_sched_barrier(0); } while (0)
#define FENCE() __builtin_amdgcn_sched_barrier(0)

__global__ __launch_bounds__(256) void st_fused_kernel(
    const float* __restrict__ src,
    const float* __restrict__ flows,
    const float* __restrict__ rfp,
    float* __restrict__ out)
{
    __shared__ float bufA[PL], bufB[PL];     // 13.4 KB channel double buffer
    __shared__ float trb[4][292];            // per-wave output transpose (4.7 KB)
    const int t = threadIdx.x;
    const int lane = t & 63;
    const int v = t >> 6;                    // wave id 0..3

    // XCD-aware bijective swizzle (2400 = 8 x 300)
    const int bid = blockIdx.x;
    const int swz = (bid & 7) * 300 + (bid >> 3);
    const int wt = swz % 20;                 // w-tile (8 w)
    const int rest = swz / 20;
    const int dt = rest % 3;                 // d-tile (32 d)
    const int hq = rest / 3;                 // h-quad 0..39
    const int w0w = wt * 8, d0 = dt * 32, h0 = hq * 4;
    const int h = h0 + v;                    // this wave's h row
    const float rf = *rfp;

    const int Z0w = (19 * w0w) >> 5;         // max 90; +5 = 95 in-bounds
    const int X0 = 53 * dt;
    const int X0a = X0 & ~3;                 // max 104; +55 = 159 in-bounds
    const int YB = (159 * h0) / 160;         // rows YB..YB+4 cover h0..h0+3

    // ---- 2 chunk addresses/thread (16B each) + LDS dword offsets ----
    const char* ap[2];
    int loff[2];
    {
        const char* fb = (const char*)flows + ((size_t)YB * Wx + X0a) * 4;
#pragma unroll
        for (int u = 0; u < 2; ++u) {
            int c = t + u * 256;
            if (c >= NCHUNK) c = NCHUNK - 1;   // dup tail: same value to same slot, benign
            int row = c / 14, ch = c - row * 14;
            int zr = row / YW, yr = row - zr * YW;
            ap[u] = fb + ((size_t)((Z0w + zr) * Hy + yr) * Wx) * 4 + ch * 16;
            loff[u] = row * XP + ch * 4;
        }
    }

    // issue: 6 independent float4 loads; commit: stage-sum (linearity) + LDS write
    float4 rg[2][3];
    auto issue_ch = [&]() {
#pragma unroll
        for (int u = 0; u < 2; ++u) {
            rg[u][0] = *(const float4*)(ap[u]);
            rg[u][1] = *(const float4*)(ap[u] + (size_t)3 * NVOX * 4);
            rg[u][2] = *(const float4*)(ap[u] + (size_t)6 * NVOX * 4);
        }
#pragma unroll
        for (int u = 0; u < 2; ++u) ap[u] += (size_t)NVOX * 4;   // next channel
    };
    auto commit_ch = [&](float* dst) {
#pragma unroll
        for (int u = 0; u < 2; ++u) {
            float4 s;
            s.x = (rg[u][0].x + rg[u][1].x) + rg[u][2].x;
            s.y = (rg[u][0].y + rg[u][1].y) + rg[u][2].y;
            s.z = (rg[u][0].z + rg[u][1].z) + rg[u][2].z;
            s.w = (rg[u][0].w + rg[u][1].w) + rg[u][2].w;
            *(float4*)(dst + loff[u]) = s;
        }
    };

    // ---- compute mapping: lanes vary d (stage-2 x axis = stride 1) ----
    const int dl = lane & 31;
    const int half = lane >> 5;              // picks w quartet
    const int d = d0 + dl;

    const float xf = (float)(53 * d) * (1.0f / 32.0f);
    const int   x0i = (int)xf;
    const float fx  = xf - (float)x0i;
    const int   xx  = x0i - X0a;             // 0..54
    const float wxa = 1.0f - fx, wxb = fx;

    // z-row factorization (4 consecutive rows cover all 4 k's z-pairs)
    int rowoff[4];
    float wkz[4][4];
    {
        int zzk[4]; float wz0k[4], wz1k[4];
#pragma unroll
        for (int k = 0; k < 4; ++k) {
            const int w = w0w + 4 * half + k;
            const float zf = (float)(19 * w) * (1.0f / 32.0f);
            const int z0i = (int)zf;
            const float fz = zf - (float)z0i;
            zzk[k] = z0i - Z0w;              // 0..4, nondecreasing
            wz0k[k] = 1.0f - fz; wz1k[k] = fz;
        }
        const int zz0 = zzk[0];
#pragma unroll
        for (int r = 0; r < 4; ++r) {
            rowoff[r] = min(zz0 + r, ZW - 1) * (YW * XP);
#pragma unroll
            for (int k = 0; k < 4; ++k) {
                const int rel = zzk[k] - zz0;
                wkz[r][k] = (rel == r) ? wz0k[k] : ((rel == r - 1) ? wz1k[k] : 0.0f);
            }
        }
    }

    // y-interp for this wave's single h: rows yrel, yrel+1 of the footprint
    const float yf = (float)h * (159.0f / 160.0f);
    const int y0i = (int)yf;
    const float fy = yf - (float)y0i;
    const int yrel = y0i - YB;               // 0..3 (wave-uniform)
    const float wy0 = 1.0f - fy, wy1 = fy;

    // 8 row-pair LDS reads per channel
    auto compute = [&](const float* buf, float (&acc)[4]) {
#pragma unroll
        for (int yy = 0; yy < 2; ++yy) {
            const float wy = yy ? wy1 : wy0;
            float zv0 = 0.f, zv1 = 0.f, zv2 = 0.f, zv3 = 0.f;
#pragma unroll
            for (int r = 0; r < 4; ++r) {
                const float* p = buf + rowoff[r] + (yrel + yy) * XP + xx;
                const float xv = wxa * p[0] + wxb * p[1];
                zv0 += wkz[r][0] * xv;
                zv1 += wkz[r][1] * xv;
                zv2 += wkz[r][2] * xv;
                zv3 += wkz[r][3] * xv;
            }
            acc[0] += wy * zv0;
            acc[1] += wy * zv1;
            acc[2] += wy * zv2;
            acc[3] += wy * zv3;
        }
    };

    float accA[4] = {0.f, 0.f, 0.f, 0.f};
    float accB[4] = {0.f, 0.f, 0.f, 0.f};
    float accC[4] = {0.f, 0.f, 0.f, 0.f};

    // ---- 3-channel block pipeline: 3 barriers total ----
    issue_ch();                  // ch0
    commit_ch(bufA);
    __syncthreads();             // bufA visible
    issue_ch();                  // ch1 (latency hides under compute)
    compute(bufA, accA);
    FENCE();
    commit_ch(bufB);
    __syncthreads();             // bufB visible; all reads of bufA done
    issue_ch();                  // ch2
    compute(bufB, accB);
    FENCE();
    commit_ch(bufA);
    __syncthreads();             // bufA (ch2) visible
    compute(bufA, accC);

    // ---- stage 2: row-paired src sampling (zeros mode) -> wave-private transpose ----
    float* tr = &trb[v][0];
#pragma unroll
    for (int k = 0; k < 4; ++k) {
        const int w = w0w + 4 * half + k;
        const float f0 = (float)d + accA[k] * rf;    // -> x axis of src
        const float f1 = (float)h + accB[k] * rf;    // -> y axis
        const float f2 = (float)w + accC[k] * rf;    // -> z axis

        const float xs = f0 * (159.0f / 95.0f);
        const float ys = f1;
        const float zs = f2 * (95.0f / 159.0f);

        const float xf0 = floorf(xs), yf0 = floorf(ys), zf0 = floorf(zs);
        const float gx = xs - xf0, gy = ys - yf0, gz = zs - zf0;
        const int xi0 = (int)xf0, yi0 = (int)yf0, zi0 = (int)zf0;

        const int xc = min(max(xi0, 0), Wx - 2);
        const bool sx0 = (xi0 == xc);
        const float wx0m = ((unsigned)xi0 < (unsigned)Wx) ? (1.0f - gx) : 0.0f;
        const float wx1m = ((unsigned)(xi0 + 1) < (unsigned)Wx) ? gx : 0.0f;

        const int yc0 = min(max(yi0, 0), Hy - 1);
        const int yc1 = min(max(yi0 + 1, 0), Hy - 1);
        const int zc0 = min(max(zi0, 0), Dz - 1);
        const int zc1 = min(max(zi0 + 1, 0), Dz - 1);
        const float wy0m = ((unsigned)yi0 < (unsigned)Hy) ? (1.0f - gy) : 0.0f;
        const float wy1m = ((unsigned)(yi0 + 1) < (unsigned)Hy) ? gy : 0.0f;
        const float wz0m = ((unsigned)zi0 < (unsigned)Dz) ? (1.0f - gz) : 0.0f;
        const float wz1m = ((unsigned)(zi0 + 1) < (unsigned)Dz) ? gz : 0.0f;

        const float w00 = wz0m * wy0m, w01 = wz0m * wy1m;
        const float w10 = wz1m * wy0m, w11 = wz1m * wy1m;

        float r = 0.0f;
        auto rowadd = [&](int zc, int yc, float wgt) {
            const float* p = src + ((size_t)zc * Hy + yc) * Wx + xc;
            const float va = p[0], vb = p[1];
            const float s0 = sx0 ? va : vb;    // value at xi0 (xi0==159 -> vb)
            const float s1 = sx0 ? vb : va;    // value at xi1 (xi0==-1 -> va)
            r += wgt * (wx0m * s0 + wx1m * s1);
        };
        rowadd(zc0, yc0, w00);
        rowadd(zc0, yc1, w01);
        rowadd(zc1, yc0, w10);
        rowadd(zc1, yc1, w11);

        tr[dl * 9 + 4 * half + k] = r;
    }
    WAIT_LGKM();

    const int rrow = lane >> 3;              // 0..7
    const int rcol = lane & 7;               // 0..7
#pragma unroll
    for (int m = 0; m < 4; ++m) {
        const int dr = m * 8 + rrow;
        out[((size_t)(d0 + dr) * Hy + h) * Wx + (w0w + rcol)] =
            tr[dr * 9 + rcol];
    }
}

extern "C" void kernel_launch(void* const* d_in, const int* in_sizes, int n_in,
                              void* d_out, int out_size, void* d_ws, size_t ws_size,
                              hipStream_t stream) {
    const float* src   = (const float*)d_in[0];
    const float* flows = (const float*)d_in[1];
    const float* rfp   = (const float*)d_in[2];
    float* out = (float*)d_out;

    st_fused_kernel<<<dim3(2400), 256, 0, stream>>>(src, flows, rfp, out);
}